// Round 1
// baseline (442.700 us; speedup 1.0000x reference)
//
#include <hip/hip_runtime.h>
#include <hip/hip_bf16.h>

// Problem constants (fixed by setup_inputs)
#define E_    8
#define DIN   2048
#define DOUT  2048
#define N_TOK 4096
#define NK    8192
#define R_    16
#define KEXT  2112            // 2048 + 16 (LoRA rank tail) + 48 zero pad, %64==0
#define KT_N  (KEXT / 64)     // 33 K-tiles
#define BM    256
#define BN    256
#define MT_MAX 40             // worst-case sum_e ceil(Me/256) = 32 + 7 (+1 slack)

typedef __bf16 bf16x8 __attribute__((ext_vector_type(8)));
typedef float  f32x4  __attribute__((ext_vector_type(4)));

static __device__ __forceinline__ void gld16(const void* g, void* l) {
  __builtin_amdgcn_global_load_lds(
      (const __attribute__((address_space(1))) unsigned int*)g,
      (__attribute__((address_space(3))) unsigned int*)l, 16, 0, 0);
}

static __device__ __forceinline__ unsigned short f2bfu(float f) {
  union { float f; unsigned int u; } v; v.f = f;
  unsigned int r = v.u + 0x7fffu + ((v.u >> 16) & 1u);  // round-to-nearest-even
  return (unsigned short)(r >> 16);
}

// ---- build Wbe[e][n][KEXT]: bf16(W) | bf16(loraB) | zeros. One 64-thr block per row ----
__global__ void __launch_bounds__(64)
k_wconv(const float* __restrict__ w, const float* __restrict__ lb,
        unsigned short* __restrict__ wbe) {
  const long long row = blockIdx.x;                 // e*DOUT + n, 0..16383
  const float4* src  = (const float4*)(w + row * DIN);
  const float4* lsrc = (const float4*)(lb + row * R_);
  ushort4* dst = (ushort4*)(wbe + row * KEXT);
  for (int u = threadIdx.x; u < KEXT / 4; u += 64) {
    float4 v;
    if (u < 512)       v = src[u];
    else if (u < 516)  v = lsrc[u - 512];
    else               v = make_float4(0.f, 0.f, 0.f, 0.f);
    ushort4 o;
    o.x = f2bfu(v.x); o.y = f2bfu(v.y); o.z = f2bfu(v.z); o.w = f2bfu(v.w);
    dst[u] = o;
  }
}

// ---- gather token rows into Xe (bf16, stride KEXT), zero the pad tail ----
// Fused side-job: first 256 blocks also convert lora_A fp32 -> bf16 (one float4/thread).
__global__ void k_gather(const float* __restrict__ x, const int* __restrict__ ssi,
                         const float* __restrict__ gates, const int* __restrict__ kptr,
                         unsigned short* __restrict__ Xe, float* __restrict__ gate,
                         int* __restrict__ tok,
                         const float* __restrict__ la, unsigned short* __restrict__ Ab) {
  int s = blockIdx.x;
  int ai = (s << 8) + threadIdx.x;                 // fused aconv: 65536 float4 total
  if (ai < (E_ * R_ * DIN / 4)) {
    float4 v = ((const float4*)la)[ai];
    ushort4 o;
    o.x = f2bfu(v.x); o.y = f2bfu(v.y); o.z = f2bfu(v.z); o.w = f2bfu(v.w);
    ((ushort4*)Ab)[ai] = o;
  }
  int ssv = ssi[s];
  int kk = kptr[0];
  int t = ssv / kk, sl = ssv - t * kk;
  if (threadIdx.x == 0) { gate[s] = gates[t * kk + sl]; tok[s] = t; }
  const float4* src = (const float4*)(x + (long long)t * DIN);
  ushort4* dst = (ushort4*)(Xe + (long long)s * KEXT);
  for (int i = threadIdx.x; i < 512; i += 256) {
    float4 v = src[i];
    ushort4 o;
    o.x = f2bfu(v.x); o.y = f2bfu(v.y); o.z = f2bfu(v.z); o.w = f2bfu(v.w);
    dst[i] = o;
  }
  if (threadIdx.x < 12) {   // zero cols 2064..2111 (XA slot 2048..2063 filled by k_xa)
    ushort4 z; z.x = z.y = z.z = z.w = 0;
    dst[516 + threadIdx.x] = z;
  }
}

// ---- XA tail via MFMA: Xe[s][2048+r] = bf16( 2 * dot(x_s, lora_A[e][r]) ) ----
__global__ void __launch_bounds__(64)
k_xa(unsigned short* __restrict__ Xe, const unsigned short* __restrict__ Ab,
     const int* __restrict__ eoff) {
  int tile = blockIdx.x;
  int off_prev = 0, e = -1, m_start = 0, m_end = 0, acc_t = 0;
#pragma unroll
  for (int i = 0; i < E_; i++) {
    int oe = eoff[i];
    int te = (oe - off_prev + 15) >> 4;
    if (e < 0 && tile < acc_t + te) {
      e = i; m_start = off_prev + (tile - acc_t) * 16; m_end = oe;
    }
    acc_t += te; off_prev = oe;
  }
  if (e < 0) return;
  const int lane = threadIdx.x;
  const int l15 = lane & 15, quad = lane >> 4;
  int arow = m_start + l15; if (arow >= m_end) arow = m_end - 1;  // clamp partial tile
  const unsigned short* xp = Xe + (long long)arow * KEXT + quad * 8;
  const unsigned short* bp = Ab + ((long long)e * R_ + l15) * DIN + quad * 8;
  f32x4 acc = (f32x4){0.f, 0.f, 0.f, 0.f};
#pragma unroll 8
  for (int k0 = 0; k0 < DIN; k0 += 32) {
    bf16x8 a = *(const bf16x8*)(xp + k0);
    bf16x8 b = *(const bf16x8*)(bp + k0);
    acc = __builtin_amdgcn_mfma_f32_16x16x32_bf16(a, b, acc, 0, 0, 0);
  }
#pragma unroll
  for (int t = 0; t < 4; t++) {
    int slot = m_start + quad * 4 + t;
    if (slot < m_end)
      Xe[(long long)slot * KEXT + 2048 + l15] = f2bfu(2.0f * acc[t]);
  }
}

// ---- grouped GEMM, 256x256 tile, 8 waves, double-buffered BK=64, 2-phase (T3-min) ----
// Schedule per K-tile: issue next tile's global_load_lds, then 24 ds_read + 64 MFMA from
// current buffer, then ONE vmcnt(0)+barrier (the __syncthreads drain). Load flight
// overlaps the 64-MFMA compute phase instead of being serially drained before it.
// LDS XOR-8 swizzle identical to the proven 128-tile version (0 bank conflicts).
// Grid 320 = MT_MAX*8, id&7 = XCD slot: n-tile fixed per XCD (nt = (id>>3)&7 varies
// within XCD, m-tiles spread mod 8 across XCDs) -> per-XCD Xe working set ~2.2 MB
// (L2-resident), same-expert blocks stream the same W K-slab in near-lockstep.
__global__ void __launch_bounds__(512, 2)
k_gemm(const unsigned short* __restrict__ Xe, const unsigned short* __restrict__ Wbe,
       const float* __restrict__ gate, const int* __restrict__ tok,
       const int* __restrict__ eoff, float* __restrict__ out) {
  __shared__ alignas(16) unsigned short sA[2][BM * 64];   // 64 KB
  __shared__ alignas(16) unsigned short sB[2][BN * 64];   // 64 KB
  __shared__ float gs[BM];
  __shared__ int   ts[BM];

  const int id  = blockIdx.x;
  const int xcd = id & 7;
  const int jb  = id >> 3;                  // 0..39
  const int nt  = jb & 7;
  const int mt  = ((jb >> 3) << 3) | xcd;   // 0..39, spread across XCDs
  const int n_start = nt << 8;

  // m-tile scan, BM=256
  int off_prev = 0, e = -1, m_start = 0, m_end = 0, acc_t = 0;
#pragma unroll
  for (int i = 0; i < E_; i++) {
    int oe = eoff[i];
    int te = (oe - off_prev + 255) >> 8;
    if (e < 0 && mt < acc_t + te) {
      e = i; m_start = off_prev + (mt - acc_t) * 256; m_end = oe;
    }
    acc_t += te;
    off_prev = oe;
  }
  if (e < 0) return;

  const int tid = threadIdx.x;
  const int w = tid >> 6, lane = tid & 63;
  const int wm = w >> 2, wn = w & 3;              // 2M x 4N waves, 128x64 out each
  const int quad = lane >> 4, l15 = lane & 15;
  const int srow = lane >> 3;                     // row within 8-row staging chunk
  const int scol = ((lane & 7) ^ srow) * 8;       // SWIZZLED source bf16 col (BK=64)

  if (tid < 256) {   // stage gates/tokens; prologue barrier makes them visible
    int gm = m_start + tid; if (gm >= m_end) gm = m_end - 1;
    gs[tid] = gate[gm];
    ts[tid] = tok[gm];
  }

  f32x4 acc[8][4];
#pragma unroll
  for (int mi = 0; mi < 8; mi++)
#pragma unroll
    for (int ni = 0; ni < 4; ni++)
      acc[mi][ni] = (f32x4){0.f, 0.f, 0.f, 0.f};

  const unsigned short* Wb = Wbe + (long long)e * DOUT * KEXT;

  // stage one BK=64 K-tile into buffer `buf`: 32 chunks x (8 rows x 64 cols) for A and B
#define STAGE(buf, kt_)                                                              \
  {                                                                                  \
    const int k0s = (kt_) * 64;                                                      \
    _Pragma("unroll")                                                                \
    for (int jj = 0; jj < 4; jj++) {                                                 \
      const int c = (w << 2) + jj;                                                   \
      const int rt = (c << 3) + srow;                                                \
      int ga = m_start + rt; if (ga >= m_end) ga = m_end - 1; /* clamp partial */    \
      gld16(Xe + (long long)ga * KEXT + k0s + scol, &sA[buf][(c << 9) + (lane << 3)]); \
      gld16(Wb + (long long)(n_start + rt) * KEXT + k0s + scol,                      \
            &sB[buf][(c << 9) + (lane << 3)]);                                       \
    }                                                                                \
  }

  STAGE(0, 0);
  __syncthreads();   // emits vmcnt(0) drain: buf0 ready, gs/ts visible

  for (int kt = 0; kt < KT_N; kt++) {
    const int b = kt & 1;
    if (kt + 1 < KT_N) STAGE(b ^ 1, kt + 1);   // prefetch overlaps compute below
#pragma unroll
    for (int ks = 0; ks < 2; ks++) {
      // swizzled read: colchunk kc lives at slot kc^(row&7); row&7 == l15&7
      const int kx = (((ks << 2) | quad) ^ (l15 & 7)) << 3;
      bf16x8 af[8], bfr[4];
#pragma unroll
      for (int mi = 0; mi < 8; mi++)
        af[mi] = *(const bf16x8*)&sA[b][(wm * 128 + mi * 16 + l15) * 64 + kx];
#pragma unroll
      for (int ni = 0; ni < 4; ni++)
        bfr[ni] = *(const bf16x8*)&sB[b][(wn * 64 + ni * 16 + l15) * 64 + kx];
#pragma unroll
      for (int mi = 0; mi < 8; mi++)
#pragma unroll
        for (int ni = 0; ni < 4; ni++)
          acc[mi][ni] = __builtin_amdgcn_mfma_f32_16x16x32_bf16(
              af[mi], bfr[ni], acc[mi][ni], 0, 0, 0);
    }
    __syncthreads();   // single drain+barrier per K-tile (dbuf makes this safe)
  }
#undef STAGE

  // ---- epilogue: gate + atomic scatter (LoRA already in acc via K-tail) ----
#pragma unroll
  for (int mi = 0; mi < 8; mi++) {
    const int rbase = wm * 128 + mi * 16 + quad * 4;
#pragma unroll
    for (int t4 = 0; t4 < 4; t4++) {
      const int row = rbase + t4;
      if (m_start + row >= m_end) continue;    // partial tile guard
      const float g = gs[row];
      float* orow = out + (long long)ts[row] * DOUT + n_start + wn * 64 + l15;
#pragma unroll
      for (int ni = 0; ni < 4; ni++)
        atomicAdd(orow + ni * 16, acc[mi][ni][t4] * g);  // exactly k=2 adds/elem
    }
  }
}

extern "C" void kernel_launch(void* const* d_in, const int* in_sizes, int n_in,
                              void* d_out, int out_size, void* d_ws, size_t ws_size,
                              hipStream_t stream) {
  (void)in_sizes; (void)n_in; (void)out_size; (void)ws_size;
  const float* inputs = (const float*)d_in[0];
  const float* weight = (const float*)d_in[1];
  const float* lora_A = (const float*)d_in[2];
  const float* lora_B = (const float*)d_in[3];
  const float* gates  = (const float*)d_in[4];
  const int* sei  = (const int*)d_in[5];
  const int* ssi  = (const int*)d_in[6];
  const int* eoff = (const int*)d_in[7];
  const int* kptr = (const int*)d_in[8];
  (void)sei;
  float* out = (float*)d_out;

  // workspace layout (~104.4 MB)
  unsigned char* ws = (unsigned char*)d_ws;
  unsigned short* Wbe = (unsigned short*)ws;                 // 8*2048*2112*2 = 69,206,016 B
  unsigned short* Xe  = (unsigned short*)(ws + 69206016);    // 8192*2112*2   = 34,603,008 B
  unsigned short* Ab  = (unsigned short*)(ws + 103809024);   // 8*16*2048*2   =    524,288 B
  float* gate = (float*)(ws + 104333312);                    // 8192*4
  int*   tok  = (int*)(ws + 104366080);                      // 8192*4

  hipMemsetAsync(d_out, 0, (size_t)N_TOK * DOUT * sizeof(float), stream);
  k_wconv<<<E_ * DOUT, 64, 0, stream>>>(weight, lora_B, Wbe);
  k_gather<<<NK, 256, 0, stream>>>(inputs, ssi, gates, kptr, Xe, gate, tok, lora_A, Ab);
  k_xa<<<519, 64, 0, stream>>>(Xe, Ab, eoff);
  k_gemm<<<MT_MAX * 8, 512, 0, stream>>>(Xe, Wbe, gate, tok, eoff, out);
}